// Round 7
// baseline (125.366 us; speedup 1.0000x reference)
//
#include <hip/hip_runtime.h>
#include <hip/hip_bf16.h>
#include <stdint.h>

// ---------------- problem constants ----------------
#define B_  4
#define N_  2048
#define C_  1024
#define E_  8
#define H_  512      // C/2

typedef __bf16 bf16x8 __attribute__((ext_vector_type(8)));
typedef __bf16 bf16x4 __attribute__((ext_vector_type(4)));
typedef float  f32x4  __attribute__((ext_vector_type(4)));

// ---------------- workspace layout (bytes) ----------------
// pmean (4 MB) overlaps Wb (8 MB): pmean consumed by mean2 BEFORE wbgate
// writes Wb (same stream, ordered) -> safe. Xb is GONE (GEMM reads f32 x).
#define WB_OFF   0ull
#define PM_OFF   0ull
#define GX_OFF   (8ull*1024*1024)
#define BB_OFF   (GX_OFF + 16384ull)
#define H_OFF    (BB_OFF + 16384ull)

__device__ __forceinline__ void gload16(const void* g, void* l) {
  __builtin_amdgcn_global_load_lds((const __attribute__((address_space(1))) void*)g,
                                   (__attribute__((address_space(3))) void*)l, 16, 0, 0);
}

#define CFENCE() asm volatile("" ::: "memory")

// ---------------- 1. mean partials over x (no cast, no atomics) ----------------
// grid 1024, block 256: 8 rows/block -> pmean[1024][1024]
__global__ __launch_bounds__(256) void meanp_kernel(const float* __restrict__ x,
                                                    float* __restrict__ pmean) {
  __shared__ float red[128][9];
  int rblk = blockIdx.x;
  int t = threadIdx.x;
  int cg = t & 127, rg = t >> 7;
  int r0 = rblk * 8 + rg * 4;
  const float4* sp = (const float4*)(x + (size_t)r0 * C_) + cg * 2;
  float s[8] = {};
  #pragma unroll
  for (int rr = 0; rr < 4; ++rr) {
    float4 a = sp[0], b4 = sp[1];
    s[0] += a.x; s[1] += a.y; s[2] += a.z; s[3] += a.w;
    s[4] += b4.x; s[5] += b4.y; s[6] += b4.z; s[7] += b4.w;
    sp += C_ / 4;
  }
  if (rg == 1) {
    #pragma unroll
    for (int j = 0; j < 8; ++j) red[cg][j] = s[j];
  }
  __syncthreads();
  if (rg == 0) {
    float4 lo, hi;
    lo.x = s[0] + red[cg][0]; lo.y = s[1] + red[cg][1];
    lo.z = s[2] + red[cg][2]; lo.w = s[3] + red[cg][3];
    hi.x = s[4] + red[cg][4]; hi.y = s[5] + red[cg][5];
    hi.z = s[6] + red[cg][6]; hi.w = s[7] + red[cg][7];
    float* pr = pmean + (size_t)rblk * C_ + cg * 8;
    *(float4*)pr = lo;
    *(float4*)(pr + 4) = hi;
  }
}

// ---------------- 2. mean stage 2: gx = sum(pmean)/N ----------------
__global__ __launch_bounds__(128) void mean2_kernel(const float* __restrict__ pmean,
                                                    float* __restrict__ gx) {
  int cs = blockIdx.x, jc = blockIdx.y, b = blockIdx.z;
  int c = cs * 128 + threadIdx.x;
  const float* p = pmean + ((size_t)b * 256 + jc * 32) * C_ + c;
  float s = 0.f;
  #pragma unroll 8
  for (int j = 0; j < 32; ++j) s += p[(size_t)j * C_];
  atomicAdd(&gx[b * C_ + c], s * (1.0f / N_));
}

// ---------------- 3. h = relu(gx @ gw1^T + gb1) ----------------
__global__ __launch_bounds__(256) void h_kernel(const float* __restrict__ gx,
    const float* __restrict__ gw1, const float* __restrict__ gb1, float* __restrict__ h) {
  __shared__ float sgx[B_][C_];
  int t = threadIdx.x;
  for (int i = t; i < B_ * C_; i += 256) sgx[i >> 10][i & 1023] = gx[i];
  __syncthreads();
  int jl = t >> 4, l16 = t & 15, b = l16 & 3, qt = l16 >> 2;
  int j = blockIdx.x * 16 + jl;
  const float4* row = (const float4*)(gw1 + (size_t)j * C_) + qt * 64;
  const float* gbase = &sgx[b][qt * 256];
  float acc = 0.f;
  #pragma unroll 8
  for (int c4 = 0; c4 < 64; ++c4) {
    float4 w = row[c4];
    acc += w.x * gbase[c4*4+0] + w.y * gbase[c4*4+1]
         + w.z * gbase[c4*4+2] + w.w * gbase[c4*4+3];
  }
  acc += __shfl_down(acc, 4, 16);
  acc += __shfl_down(acc, 8, 16);
  if (qt == 0) h[b * H_ + j] = fmaxf(acc + gb1[j], 0.f);
}

// ---------------- 4. gates (recomputed per block) + Wb build + bb ----------------
__global__ __launch_bounds__(256) void wbgate_kernel(const float* __restrict__ h,
    const float* __restrict__ gw2, const float* __restrict__ gb2,
    const float* __restrict__ be, const float* __restrict__ We,
    __bf16* __restrict__ Wb, float* __restrict__ bbp) {
  __shared__ float slog[B_ * E_];
  __shared__ float sg[B_ * E_];
  int t = threadIdx.x;
  int p = t >> 3, sub = t & 7;
  int pb = p >> 3, pe = p & 7;
  float s = 0.f;
  for (int k = sub; k < H_; k += 8) s += h[pb * H_ + k] * gw2[pe * H_ + k];
  s += __shfl_down(s, 4, 8);
  s += __shfl_down(s, 2, 8);
  s += __shfl_down(s, 1, 8);
  if (sub == 0) slog[p] = s + gb2[pe];
  __syncthreads();
  if (t < B_) {
    float m = -1e30f;
    for (int e = 0; e < E_; ++e) m = fmaxf(m, slog[t * E_ + e]);
    float pr[E_], sum = 0.f;
    for (int e = 0; e < E_; ++e) { pr[e] = __expf(slog[t * E_ + e] - m); sum += pr[e]; }
    float inv = 1.f / sum;
    for (int e = 0; e < E_; ++e) sg[t * E_ + e] = pr[e] * inv;
  }
  __syncthreads();

  int bi = blockIdx.x;
  size_t i = (size_t)bi * 256 + t;
  int b = (int)(i >> 18);
  size_t oc4 = i & ((1u << 18) - 1);
  float gl[E_];
  #pragma unroll
  for (int e = 0; e < E_; ++e) gl[e] = sg[b * E_ + e];
  const float4* src = (const float4*)We + oc4;
  float4 acc = make_float4(0.f, 0.f, 0.f, 0.f);
  #pragma unroll
  for (int e = 0; e < E_; ++e) {
    float4 w = src[(size_t)e * (C_ * C_ / 4)];
    acc.x += gl[e] * w.x; acc.y += gl[e] * w.y;
    acc.z += gl[e] * w.z; acc.w += gl[e] * w.w;
  }
  bf16x4 o;
  o[0] = (__bf16)acc.x; o[1] = (__bf16)acc.y; o[2] = (__bf16)acc.z; o[3] = (__bf16)acc.w;
  *(bf16x4*)(Wb + i * 4) = o;

  if (bi < 16) {
    int ii = bi * 256 + t;
    int bb_ = ii >> 10, oo = ii & 1023;
    float sbb = 0.f;
    #pragma unroll
    for (int e = 0; e < E_; ++e) sbb += sg[bb_ * E_ + e] * be[e * C_ + oo];
    bbp[ii] = sbb;
  }
}

// ---------------- 5. fused batched GEMM: out = cast_bf16(x|x_ir) @ Wb^T + bb ----
// 256x256 tile, BK=64, 8 waves (2Mx4N), 16x16x32 MFMA (proven R4 frag path).
// A: f32 reg-staged (issue-early / cvt+ds_write-late, swizzled write).
// B: global_load_lds with pre-swizzled source. One barrier per tile.
#define NT 16   // K / 64

__global__ __launch_bounds__(512, 2) void moe_gemm(const float* __restrict__ x,
    const float* __restrict__ x_ir, const __bf16* __restrict__ Wb,
    const float* __restrict__ bb, float* __restrict__ out) {
  __shared__ __attribute__((aligned(128))) char smem[2][65536];

  const int t = threadIdx.x;
  const int wid = t >> 6, lane = t & 63;
  const int wm = wid >> 2, wn = wid & 3;

  // XCD swizzle: one z-slice per XCD
  int f = blockIdx.x;
  int swz = (f & 7) * 32 + (f >> 3);
  int xb_ = swz & 3, yb_ = (swz >> 2) & 7, z = swz >> 5;
  int b = z & 3;
  const size_t mat = (size_t)N_ * C_;
  const float* A = ((z >> 2) ? x_ir : x) + (size_t)b * mat;
  const __bf16* Bm = Wb + (size_t)b * C_ * C_;
  float* O = out + (size_t)z * mat;
  const int row0 = yb_ * 256, col0 = xb_ * 256;

  // B staging constants (pre-swizzled global src, linear gload_lds dest)
  const int lrow8 = lane >> 3;
  const int kblk  = ((lane & 7) ^ lrow8) << 3;
  // A reg-staging mapping: thread -> (row ar, k-half ahf)
  const int ar = t >> 1, ahf = t & 1;
  const int ar7 = ar & 7;
  // frag-read constants
  const int lr = lane & 15;
  const int swzk0 = (((lane >> 4) + 0) ^ (lane & 7)) << 4;
  const int swzk1 = (((lane >> 4) + 4) ^ (lane & 7)) << 4;

  auto stageB = [&](int sid, int k0, char* buf) {
    #pragma unroll
    for (int j = 0; j < 2; ++j) {
      int u = wid * 2 + j, rl0 = u * 8;
      int hh = (sid == 2) ? 1 : 0;
      int col_u = (rl0 & 31) + (rl0 >> 5) * 64 + hh * 32;
      const __bf16* src = Bm + (size_t)(col0 + col_u + lrow8) * C_ + k0 + kblk;
      gload16(src, buf + 32768 + col_u * 128);
    }
  };

  float4 AL[4];
  auto issueA = [&](int k0, int batch) {
    const float4* ap = (const float4*)(A + (size_t)(row0 + ar) * C_ + k0 + ahf * 32)
                       + batch * 4;
    AL[0] = ap[0]; AL[1] = ap[1]; AL[2] = ap[2]; AL[3] = ap[3];
  };
  auto writeA = [&](char* buf, int batch) {
    #pragma unroll
    for (int c = 0; c < 2; ++c) {
      float4 lo = AL[2 * c], hi = AL[2 * c + 1];
      bf16x8 o;
      o[0] = (__bf16)lo.x; o[1] = (__bf16)lo.y; o[2] = (__bf16)lo.z; o[3] = (__bf16)lo.w;
      o[4] = (__bf16)hi.x; o[5] = (__bf16)hi.y; o[6] = (__bf16)hi.z; o[7] = (__bf16)hi.w;
      int jg = ahf * 4 + batch * 2 + c;        // k-chunk index 0..7
      *(bf16x8*)(buf + ar * 128 + ((jg ^ ar7) << 4)) = o;   // T2 swizzled write
    }
  };

  f32x4 acc[8][4] = {};
  bf16x8 av[4][2];        // current A half-tile quadrant (overwritten mid-tile)
  bf16x8 bv[2][2][2];     // all B frags

  #define RD_A(mq_) { \
    int rby = (wm * 128 + Aq * 64 + (mq_) * 16 + lr) * 128; \
    av[mq_][0] = *(const bf16x8*)(rbA + rby + swzk0); \
    av[mq_][1] = *(const bf16x8*)(rbA + rby + swzk1); }
  #define RD_B(Bq_, nq_) { \
    int cby = (wn * 64 + (Bq_) * 32 + (nq_) * 16 + lr) * 128; \
    bv[Bq_][nq_][0] = *(const bf16x8*)(rbB + cby + swzk0); \
    bv[Bq_][nq_][1] = *(const bf16x8*)(rbB + cby + swzk1); }
  #define MFMA1(ai_, mq_, Bq_, nq_) { \
    acc[(ai_)*4+(mq_)][(Bq_)*2+(nq_)] = __builtin_amdgcn_mfma_f32_16x16x32_bf16( \
        av[mq_][0], bv[Bq_][nq_][0], acc[(ai_)*4+(mq_)][(Bq_)*2+(nq_)], 0, 0, 0); \
    acc[(ai_)*4+(mq_)][(Bq_)*2+(nq_)] = __builtin_amdgcn_mfma_f32_16x16x32_bf16( \
        av[mq_][1], bv[Bq_][nq_][1], acc[(ai_)*4+(mq_)][(Bq_)*2+(nq_)], 0, 0, 0); }

  // prologue: fill buf0 (A via regs, B via gload_lds)
  issueA(0, 0);
  stageB(1, 0, smem[0]); stageB(2, 0, smem[0]);
  writeA(smem[0], 0);            // compiler auto-waits the AL loads
  issueA(0, 1);
  writeA(smem[0], 1);
  asm volatile("s_waitcnt vmcnt(0)" ::: "memory");
  asm volatile("s_waitcnt lgkmcnt(0)" ::: "memory");
  __builtin_amdgcn_s_barrier();
  CFENCE();

  for (int kt = 0; kt < NT; ++kt) {
    const char* rbA = smem[kt & 1];
    const char* rbB = rbA + 32768;
    char* wbuf = smem[(kt + 1) & 1];
    const bool more = kt + 1 < NT;
    const int knext = (kt + 1) * 64;

    // issue next-tile loads early (T14)
    if (more) { issueA(knext, 0); stageB(1, knext, wbuf); stageB(2, knext, wbuf); }

    // ---- half 1: A-quadrant 0 x all B ----
    {
      const int Aq = 0;
      RD_A(0) RD_A(1) RD_A(2) RD_A(3)
      RD_B(0, 0) RD_B(0, 1) RD_B(1, 0) RD_B(1, 1)
      __builtin_amdgcn_s_setprio(1);
      MFMA1(0, 0, 0, 0) MFMA1(0, 0, 0, 1) MFMA1(0, 1, 0, 0) MFMA1(0, 1, 0, 1)
      MFMA1(0, 2, 0, 0) MFMA1(0, 2, 0, 1) MFMA1(0, 3, 0, 0) MFMA1(0, 3, 0, 1)
      MFMA1(0, 0, 1, 0) MFMA1(0, 0, 1, 1) MFMA1(0, 1, 1, 0) MFMA1(0, 1, 1, 1)
      MFMA1(0, 2, 1, 0) MFMA1(0, 2, 1, 1) MFMA1(0, 3, 1, 0) MFMA1(0, 3, 1, 1)
      __builtin_amdgcn_s_setprio(0);
    }
    // mid-tile: retire A-batch0 into next buf, issue batch1
    if (more) { writeA(wbuf, 0); issueA(knext, 1); }

    // ---- half 2: A-quadrant 1 x all B (av overwritten) ----
    {
      const int Aq = 1;
      RD_A(0) RD_A(1) RD_A(2) RD_A(3)
      __builtin_amdgcn_s_setprio(1);
      MFMA1(1, 0, 0, 0) MFMA1(1, 0, 0, 1) MFMA1(1, 1, 0, 0) MFMA1(1, 1, 0, 1)
      MFMA1(1, 2, 0, 0) MFMA1(1, 2, 0, 1) MFMA1(1, 3, 0, 0) MFMA1(1, 3, 0, 1)
      MFMA1(1, 0, 1, 0) MFMA1(1, 0, 1, 1) MFMA1(1, 1, 1, 0) MFMA1(1, 1, 1, 1)
      MFMA1(1, 2, 1, 0) MFMA1(1, 2, 1, 1) MFMA1(1, 3, 1, 0) MFMA1(1, 3, 1, 1)
      __builtin_amdgcn_s_setprio(0);
    }
    if (more) { writeA(wbuf, 1); }

    // single end-of-tile drain + barrier (dbuf WAR-safe; see analysis)
    asm volatile("s_waitcnt vmcnt(0)" ::: "memory");
    asm volatile("s_waitcnt lgkmcnt(0)" ::: "memory");
    __builtin_amdgcn_s_barrier();
    CFENCE();
  }

  // ---- coalesced epilogue via per-wave LDS transpose (16 x 68 f32) ----
  // C/D map col=lane&15, row=(lane>>4)*4+reg  [m89-verified]
  float* eb = (float*)(smem[0]) + wid * (16 * 68);
  const int er = lane >> 4;
  const f32x4 bias4 = *(const f32x4*)(bb + b * C_ + col0 + wn * 64 + lr * 4);

  #pragma unroll
  for (int m = 0; m < 8; ++m) {
    #pragma unroll
    for (int n = 0; n < 4; ++n) {
      f32x4 v = acc[m][n];
      #pragma unroll
      for (int r = 0; r < 4; ++r)
        eb[(er * 4 + r) * 68 + n * 16 + lr] = v[r];
    }
    asm volatile("s_waitcnt lgkmcnt(0)" ::: "memory");
    __builtin_amdgcn_sched_barrier(0);
    #pragma unroll
    for (int j = 0; j < 4; ++j) {
      int row = j * 4 + er;
      f32x4 v = *(const f32x4*)(eb + row * 68 + lr * 4);
      v[0] += bias4[0]; v[1] += bias4[1]; v[2] += bias4[2]; v[3] += bias4[3];
      int grow = row0 + wm * 128 + m * 16 + row;
      int gcol = col0 + wn * 64 + lr * 4;
      *(f32x4*)(O + (size_t)grow * C_ + gcol) = v;
    }
    asm volatile("s_waitcnt lgkmcnt(0)" ::: "memory");
  }
}

// ---------------- launcher ----------------
extern "C" void kernel_launch(void* const* d_in, const int* in_sizes, int n_in,
                              void* d_out, int out_size, void* d_ws, size_t ws_size,
                              hipStream_t stream) {
  const float* x    = (const float*)d_in[0];
  const float* x_ir = (const float*)d_in[1];
  const float* We   = (const float*)d_in[2];
  const float* be   = (const float*)d_in[3];
  const float* gw1  = (const float*)d_in[4];
  const float* gb1  = (const float*)d_in[5];
  const float* gw2  = (const float*)d_in[6];
  const float* gb2  = (const float*)d_in[7];
  float* out = (float*)d_out;

  char* ws = (char*)d_ws;
  __bf16* Wb    = (__bf16*)(ws + WB_OFF);
  float*  pmean = (float*)(ws + PM_OFF);   // overlaps Wb (ordered: mean2 < wbgate)
  float*  gx    = (float*)(ws + GX_OFF);
  float*  bbp   = (float*)(ws + BB_OFF);
  float*  h     = (float*)(ws + H_OFF);

  hipMemsetAsync(gx, 0, B_ * C_ * sizeof(float), stream);

  meanp_kernel<<<1024, 256, 0, stream>>>(x, pmean);
  mean2_kernel<<<dim3(8, 8, 4), 128, 0, stream>>>(pmean, gx);
  h_kernel<<<32, 256, 0, stream>>>(gx, gw1, gb1, h);
  wbgate_kernel<<<4096, 256, 0, stream>>>(h, gw2, gb2, be, We, Wb, bbp);

  moe_gemm<<<256, 512, 0, stream>>>(x, x_ir, Wb, bbp, out);
}

// Round 8
// 118.620 us; speedup vs baseline: 1.0569x; 1.0569x over previous
//
#include <hip/hip_runtime.h>
#include <hip/hip_bf16.h>
#include <stdint.h>

// ---------------- problem constants ----------------
#define B_  4
#define N_  2048
#define C_  1024
#define E_  8
#define H_  512      // C/2

typedef __bf16 bf16x8 __attribute__((ext_vector_type(8)));
typedef __bf16 bf16x4 __attribute__((ext_vector_type(4)));
typedef float  f32x4  __attribute__((ext_vector_type(4)));

// ---------------- workspace layout (bytes) ----------------
// pmean (4 MB) overlaps Wb (8 MB): pmean consumed by mean2 BEFORE wbgate
// writes Wb (same stream, ordered) -> safe.
#define WB_OFF   0ull
#define PM_OFF   0ull
#define XB_OFF   (8ull*1024*1024)
#define GX_OFF   (XB_OFF + 32ull*1024*1024)
#define BB_OFF   (GX_OFF + 16384ull)
#define H_OFF    (BB_OFF + 16384ull)

__device__ __forceinline__ void gload16(const void* g, void* l) {
  __builtin_amdgcn_global_load_lds((const __attribute__((address_space(1))) void*)g,
                                   (__attribute__((address_space(3))) void*)l, 16, 0, 0);
}

#define CFENCE() asm volatile("" ::: "memory")

// ---------------- 1. fused f32->bf16 cast + mean PARTIALS (no atomics) ----------------
// grid 2048: blocks 0-1023 -> x (write pmean row), 1024-2047 -> x_ir. 8 rows/block.
__global__ __launch_bounds__(256) void castmean_kernel(const float* __restrict__ x,
    const float* __restrict__ x_ir, __bf16* __restrict__ dst, float* __restrict__ pmean) {
  __shared__ float red[128][9];
  int bi = blockIdx.x;
  int half = bi >> 10, rblk = bi & 1023;
  const float* src = half ? x_ir : x;
  int t = threadIdx.x;
  int cg = t & 127, rg = t >> 7;
  int r0 = rblk * 8 + rg * 4;
  const float4* sp = (const float4*)(src + (size_t)r0 * C_) + cg * 2;
  __bf16* dp = dst + (size_t)half * ((size_t)B_ * N_ * C_) + (size_t)r0 * C_ + cg * 8;
  float s[8] = {};
  #pragma unroll
  for (int rr = 0; rr < 4; ++rr) {
    float4 a = sp[0], b4 = sp[1];
    bf16x8 o;
    o[0] = (__bf16)a.x; o[1] = (__bf16)a.y; o[2] = (__bf16)a.z; o[3] = (__bf16)a.w;
    o[4] = (__bf16)b4.x; o[5] = (__bf16)b4.y; o[6] = (__bf16)b4.z; o[7] = (__bf16)b4.w;
    *(bf16x8*)dp = o;
    s[0] += a.x; s[1] += a.y; s[2] += a.z; s[3] += a.w;
    s[4] += b4.x; s[5] += b4.y; s[6] += b4.z; s[7] += b4.w;
    sp += C_ / 4; dp += C_;
  }
  if (half == 0) {
    if (rg == 1) {
      #pragma unroll
      for (int j = 0; j < 8; ++j) red[cg][j] = s[j];
    }
    __syncthreads();
    if (rg == 0) {
      float4 lo, hi;
      lo.x = s[0] + red[cg][0]; lo.y = s[1] + red[cg][1];
      lo.z = s[2] + red[cg][2]; lo.w = s[3] + red[cg][3];
      hi.x = s[4] + red[cg][4]; hi.y = s[5] + red[cg][5];
      hi.z = s[6] + red[cg][6]; hi.w = s[7] + red[cg][7];
      float* pr = pmean + (size_t)rblk * C_ + cg * 8;
      *(float4*)pr = lo;
      *(float4*)(pr + 4) = hi;
    }
  }
}

// ---------------- 2. mean stage 2 (no atomics, no memset needed) ----------------
// grid (8 cs, 4 b), block 128: block owns 128 cols, sums all 256 partial rows
__global__ __launch_bounds__(128) void mean2_kernel(const float* __restrict__ pmean,
                                                    float* __restrict__ gx) {
  int cs = blockIdx.x, b = blockIdx.y;
  int c = cs * 128 + threadIdx.x;
  const float* p = pmean + (size_t)b * 256 * C_ + c;
  float s = 0.f;
  #pragma unroll 8
  for (int j = 0; j < 256; ++j) s += p[(size_t)j * C_];
  gx[b * C_ + c] = s * (1.0f / N_);
}

// ---------------- 3. h = relu(gx @ gw1^T + gb1) ----------------
__global__ __launch_bounds__(256) void h_kernel(const float* __restrict__ gx,
    const float* __restrict__ gw1, const float* __restrict__ gb1, float* __restrict__ h) {
  __shared__ float sgx[B_][C_];
  int t = threadIdx.x;
  for (int i = t; i < B_ * C_; i += 256) sgx[i >> 10][i & 1023] = gx[i];
  __syncthreads();
  int jl = t >> 4, l16 = t & 15, b = l16 & 3, qt = l16 >> 2;
  int j = blockIdx.x * 16 + jl;
  const float4* row = (const float4*)(gw1 + (size_t)j * C_) + qt * 64;
  const float* gbase = &sgx[b][qt * 256];
  float acc = 0.f;
  #pragma unroll 8
  for (int c4 = 0; c4 < 64; ++c4) {
    float4 w = row[c4];
    acc += w.x * gbase[c4*4+0] + w.y * gbase[c4*4+1]
         + w.z * gbase[c4*4+2] + w.w * gbase[c4*4+3];
  }
  acc += __shfl_down(acc, 4, 16);
  acc += __shfl_down(acc, 8, 16);
  if (qt == 0) h[b * H_ + j] = fmaxf(acc + gb1[j], 0.f);
}

// ---------------- 4. gates (recomputed per block) + Wb build + bb ----------------
__global__ __launch_bounds__(256) void wbgate_kernel(const float* __restrict__ h,
    const float* __restrict__ gw2, const float* __restrict__ gb2,
    const float* __restrict__ be, const float* __restrict__ We,
    __bf16* __restrict__ Wb, float* __restrict__ bbp) {
  __shared__ float slog[B_ * E_];
  __shared__ float sg[B_ * E_];
  int t = threadIdx.x;
  int p = t >> 3, sub = t & 7;
  int pb = p >> 3, pe = p & 7;
  float s = 0.f;
  for (int k = sub; k < H_; k += 8) s += h[pb * H_ + k] * gw2[pe * H_ + k];
  s += __shfl_down(s, 4, 8);
  s += __shfl_down(s, 2, 8);
  s += __shfl_down(s, 1, 8);
  if (sub == 0) slog[p] = s + gb2[pe];
  __syncthreads();
  if (t < B_) {
    float m = -1e30f;
    for (int e = 0; e < E_; ++e) m = fmaxf(m, slog[t * E_ + e]);
    float pr[E_], sum = 0.f;
    for (int e = 0; e < E_; ++e) { pr[e] = __expf(slog[t * E_ + e] - m); sum += pr[e]; }
    float inv = 1.f / sum;
    for (int e = 0; e < E_; ++e) sg[t * E_ + e] = pr[e] * inv;
  }
  __syncthreads();

  int bi = blockIdx.x;
  size_t i = (size_t)bi * 256 + t;
  int b = (int)(i >> 18);
  size_t oc4 = i & ((1u << 18) - 1);
  float gl[E_];
  #pragma unroll
  for (int e = 0; e < E_; ++e) gl[e] = sg[b * E_ + e];
  const float4* src = (const float4*)We + oc4;
  float4 acc = make_float4(0.f, 0.f, 0.f, 0.f);
  #pragma unroll
  for (int e = 0; e < E_; ++e) {
    float4 w = src[(size_t)e * (C_ * C_ / 4)];
    acc.x += gl[e] * w.x; acc.y += gl[e] * w.y;
    acc.z += gl[e] * w.z; acc.w += gl[e] * w.w;
  }
  bf16x4 o;
  o[0] = (__bf16)acc.x; o[1] = (__bf16)acc.y; o[2] = (__bf16)acc.z; o[3] = (__bf16)acc.w;
  *(bf16x4*)(Wb + i * 4) = o;

  if (bi < 16) {
    int ii = bi * 256 + t;
    int bb_ = ii >> 10, oo = ii & 1023;
    float sbb = 0.f;
    #pragma unroll
    for (int e = 0; e < E_; ++e) sbb += sg[bb_ * E_ + e] * be[e * C_ + oo];
    bbp[ii] = sbb;
  }
}

// ---------------- 5. batched GEMM: out = Xb @ Wb^T + bb  (R4-proven 16x16 path) ----
// 256x256 tile, BK=64, 8 waves (2Mx4N). Stages u0,u1 in P0 and u2,u3 in P1;
// ds_reads pipelined one phase ahead; 3 barriers/tile; counted vmcnt only.
#define NT 16   // K / 64

__global__ __launch_bounds__(512, 2) void moe_gemm(const __bf16* __restrict__ Xb,
    const __bf16* __restrict__ Wb, const float* __restrict__ bb, float* __restrict__ out) {
  __shared__ __attribute__((aligned(128))) char smem[2][65536];

  const int t = threadIdx.x;
  const int wid = t >> 6, lane = t & 63;
  const int wm = wid >> 2, wn = wid & 3;

  // XCD swizzle: one z-slice per XCD
  int f = blockIdx.x;
  int swz = (f & 7) * 32 + (f >> 3);
  int xb_ = swz & 3, yb_ = (swz >> 2) & 7, z = swz >> 5;
  int b = z & 3;
  const size_t mat = (size_t)N_ * C_;
  const __bf16* A  = Xb + (size_t)z * mat;
  const __bf16* Bm = Wb + (size_t)b * C_ * C_;
  float* O = out + (size_t)z * mat;
  const int row0 = yb_ * 256, col0 = xb_ * 256;

  // staging lane constants (pre-swizzled global src, linear LDS dest)
  const int lrow8 = lane >> 3;
  const int kblk  = ((lane & 7) ^ lrow8) << 3;

  // ds-read lane constants
  const int lr = lane & 15;
  const int swzk0 = (((lane >> 4) + 0) ^ (lane & 7)) << 4;
  const int swzk1 = (((lane >> 4) + 4) ^ (lane & 7)) << 4;

  auto stage = [&](int sid, int k0, char* buf) {
    #pragma unroll
    for (int j = 0; j < 2; ++j) {
      int u = wid * 2 + j;
      int rl0 = u * 8;
      if (sid == 0 || sid == 3) {           // A
        int hh = (sid == 3) ? 1 : 0;
        int row_u = rl0 + (rl0 & 64) + hh * 64;
        const __bf16* src = A + (size_t)(row0 + row_u + lrow8) * C_ + k0 + kblk;
        gload16(src, buf + row_u * 128);
      } else {                              // B
        int hh = (sid == 2) ? 1 : 0;
        int col_u = (rl0 & 31) + (rl0 >> 5) * 64 + hh * 32;
        const __bf16* src = Bm + (size_t)(col0 + col_u + lrow8) * C_ + k0 + kblk;
        gload16(src, buf + 32768 + col_u * 128);
      }
    }
  };

  f32x4 acc[8][4] = {};
  bf16x8 av[2][4][2];     // [pipeline buf][mq][ks]
  bf16x8 bv[2][2][2];     // [Bq][nq][ks]

  #define RD_A(buf_, Aq_, mq_) { \
    int rby = (wm * 128 + (Aq_) * 64 + (mq_) * 16 + lr) * 128; \
    av[buf_][mq_][0] = *(const bf16x8*)(rbA + rby + swzk0); \
    av[buf_][mq_][1] = *(const bf16x8*)(rbA + rby + swzk1); }
  #define RD_B(Bq_, nq_) { \
    int cby = (wn * 64 + (Bq_) * 32 + (nq_) * 16 + lr) * 128; \
    bv[Bq_][nq_][0] = *(const bf16x8*)(rbB + cby + swzk0); \
    bv[Bq_][nq_][1] = *(const bf16x8*)(rbB + cby + swzk1); }
  #define MFMA1(ab_, mq_, Bq_, nq_) { \
    acc[(ab_)*4+(mq_)][(Bq_)*2+(nq_)] = __builtin_amdgcn_mfma_f32_16x16x32_bf16( \
        av[ab_][mq_][0], bv[Bq_][nq_][0], acc[(ab_)*4+(mq_)][(Bq_)*2+(nq_)], 0, 0, 0); \
    acc[(ab_)*4+(mq_)][(Bq_)*2+(nq_)] = __builtin_amdgcn_mfma_f32_16x16x32_bf16( \
        av[ab_][mq_][1], bv[Bq_][nq_][1], acc[(ab_)*4+(mq_)][(Bq_)*2+(nq_)], 0, 0, 0); }

  // prologue: stage all 4 units of tile 0; wait u0,u1 (P0 reads) + u2 (B1 lookahead)
  #pragma unroll
  for (int sid = 0; sid < 4; ++sid) stage(sid, 0, smem[0]);
  asm volatile("s_waitcnt vmcnt(2)" ::: "memory");
  __builtin_amdgcn_s_barrier();
  CFENCE();

  for (int kt = 0; kt < NT; ++kt) {
    const char* rbA = smem[kt & 1];
    const char* rbB = rbA + 32768;
    char* wbuf = smem[(kt + 1) & 1];
    const bool more = (kt + 1 < NT);
    const int knext = (kt + 1) * 64;

    // ---- P0: stage u0,u1 | read A0,B0 | MFMA A0xB0 (+lookahead read B1) ----
    if (more) { stage(0, knext, wbuf); stage(1, knext, wbuf); }
    RD_A(0, 0, 0) RD_B(0, 0) RD_A(0, 0, 1) RD_B(0, 1) RD_A(0, 0, 2) RD_A(0, 0, 3)
    __builtin_amdgcn_s_setprio(1);
    MFMA1(0, 0, 0, 0) MFMA1(0, 0, 0, 1)
    RD_B(1, 0) RD_B(1, 1)                          // lookahead for P1
    MFMA1(0, 1, 0, 0) MFMA1(0, 1, 0, 1)
    MFMA1(0, 2, 0, 0) MFMA1(0, 2, 0, 1)
    MFMA1(0, 3, 0, 0) MFMA1(0, 3, 0, 1)
    __builtin_amdgcn_s_setprio(0);
    if (more) asm volatile("s_waitcnt vmcnt(4)" ::: "memory");   // u3(cur) done
    else      asm volatile("s_waitcnt vmcnt(0)" ::: "memory");
    __builtin_amdgcn_s_barrier();
    CFENCE();

    // ---- P1: stage u2,u3 | MFMA A0xB1 (+lookahead read A1) ----
    if (more) { stage(2, knext, wbuf); stage(3, knext, wbuf); }
    __builtin_amdgcn_s_setprio(1);
    MFMA1(0, 0, 1, 0) MFMA1(0, 0, 1, 1)
    RD_A(1, 1, 0) RD_A(1, 1, 1)                    // lookahead for P23
    MFMA1(0, 1, 1, 0) MFMA1(0, 1, 1, 1)
    RD_A(1, 1, 2) RD_A(1, 1, 3)
    MFMA1(0, 2, 1, 0) MFMA1(0, 2, 1, 1)
    MFMA1(0, 3, 1, 0) MFMA1(0, 3, 1, 1)
    __builtin_amdgcn_s_setprio(0);
    __builtin_amdgcn_s_barrier();
    CFENCE();

    // ---- P23: MFMA A1xB0, A1xB1 ----
    __builtin_amdgcn_s_setprio(1);
    MFMA1(1, 0, 0, 0) MFMA1(1, 0, 0, 1) MFMA1(1, 1, 0, 0) MFMA1(1, 1, 0, 1)
    MFMA1(1, 2, 0, 0) MFMA1(1, 2, 0, 1) MFMA1(1, 3, 0, 0) MFMA1(1, 3, 0, 1)
    MFMA1(1, 0, 1, 0) MFMA1(1, 0, 1, 1) MFMA1(1, 1, 1, 0) MFMA1(1, 1, 1, 1)
    MFMA1(1, 2, 1, 0) MFMA1(1, 2, 1, 1) MFMA1(1, 3, 1, 0) MFMA1(1, 3, 1, 1)
    __builtin_amdgcn_s_setprio(0);
    if (more) asm volatile("s_waitcnt vmcnt(2)" ::: "memory");   // u0,u1,u2(next) done
    __builtin_amdgcn_s_barrier();
    CFENCE();
  }

  // ---- coalesced epilogue via per-wave LDS transpose (16 x 68 f32) ----
  float* eb = (float*)(smem[0]) + wid * (16 * 68);
  const int er = lane >> 4;
  const f32x4 bias4 = *(const f32x4*)(bb + b * C_ + col0 + wn * 64 + lr * 4);

  #pragma unroll
  for (int m = 0; m < 8; ++m) {
    #pragma unroll
    for (int n = 0; n < 4; ++n) {
      f32x4 v = acc[m][n];
      #pragma unroll
      for (int r = 0; r < 4; ++r)
        eb[(er * 4 + r) * 68 + n * 16 + lr] = v[r];
    }
    asm volatile("s_waitcnt lgkmcnt(0)" ::: "memory");
    __builtin_amdgcn_sched_barrier(0);
    #pragma unroll
    for (int j = 0; j < 4; ++j) {
      int row = j * 4 + er;
      f32x4 v = *(const f32x4*)(eb + row * 68 + lr * 4);
      v[0] += bias4[0]; v[1] += bias4[1]; v[2] += bias4[2]; v[3] += bias4[3];
      int grow = row0 + wm * 128 + m * 16 + row;
      int gcol = col0 + wn * 64 + lr * 4;
      *(f32x4*)(O + (size_t)grow * C_ + gcol) = v;
    }
    asm volatile("s_waitcnt lgkmcnt(0)" ::: "memory");
  }
}

// ---------------- launcher ----------------
extern "C" void kernel_launch(void* const* d_in, const int* in_sizes, int n_in,
                              void* d_out, int out_size, void* d_ws, size_t ws_size,
                              hipStream_t stream) {
  const float* x    = (const float*)d_in[0];
  const float* x_ir = (const float*)d_in[1];
  const float* We   = (const float*)d_in[2];
  const float* be   = (const float*)d_in[3];
  const float* gw1  = (const float*)d_in[4];
  const float* gb1  = (const float*)d_in[5];
  const float* gw2  = (const float*)d_in[6];
  const float* gb2  = (const float*)d_in[7];
  float* out = (float*)d_out;

  char* ws = (char*)d_ws;
  __bf16* Wb    = (__bf16*)(ws + WB_OFF);
  float*  pmean = (float*)(ws + PM_OFF);   // overlaps Wb (ordered: mean2 < wbgate)
  __bf16* Xb    = (__bf16*)(ws + XB_OFF);
  float*  gx    = (float*)(ws + GX_OFF);
  float*  bbp   = (float*)(ws + BB_OFF);
  float*  h     = (float*)(ws + H_OFF);

  castmean_kernel<<<2048, 256, 0, stream>>>(x, x_ir, Xb, pmean);
  mean2_kernel<<<dim3(8, 4), 128, 0, stream>>>(pmean, gx);
  h_kernel<<<32, 256, 0, stream>>>(gx, gw1, gb1, h);
  wbgate_kernel<<<4096, 256, 0, stream>>>(h, gw2, gb2, be, We, Wb, bbp);

  moe_gemm<<<256, 512, 0, stream>>>(Xb, Wb, bbp, out);
}

// Round 9
// 91.652 us; speedup vs baseline: 1.3678x; 1.2942x over previous
//
#include <hip/hip_runtime.h>
#include <hip/hip_bf16.h>
#include <stdint.h>

// ---------------- problem constants ----------------
#define B_  4
#define N_  2048
#define C_  1024
#define E_  8
#define H_  512      // C/2

typedef __bf16 bf16x8 __attribute__((ext_vector_type(8)));
typedef __bf16 bf16x4 __attribute__((ext_vector_type(4)));
typedef float  f32x4  __attribute__((ext_vector_type(4)));

// ---------------- workspace layout (bytes) ----------------
// pmean (4 MB) overlaps Wb (8 MB): pmean consumed by mean2 BEFORE wbgate
// writes Wb (same stream, ordered) -> safe.
#define WB_OFF   0ull
#define PM_OFF   0ull
#define XB_OFF   (8ull*1024*1024)
#define GX_OFF   (XB_OFF + 32ull*1024*1024)
#define BB_OFF   (GX_OFF + 16384ull)
#define H_OFF    (BB_OFF + 16384ull)

__device__ __forceinline__ void gload16(const void* g, void* l) {
  __builtin_amdgcn_global_load_lds((const __attribute__((address_space(1))) void*)g,
                                   (__attribute__((address_space(3))) void*)l, 16, 0, 0);
}

#define CFENCE() asm volatile("" ::: "memory")

// ---------------- 1. fused f32->bf16 cast + mean PARTIALS (no atomics) ----------------
// grid 2048: blocks 0-1023 -> x (write pmean row), 1024-2047 -> x_ir. 8 rows/block.
__global__ __launch_bounds__(256) void castmean_kernel(const float* __restrict__ x,
    const float* __restrict__ x_ir, __bf16* __restrict__ dst, float* __restrict__ pmean) {
  __shared__ float red[128][9];
  int bi = blockIdx.x;
  int half = bi >> 10, rblk = bi & 1023;
  const float* src = half ? x_ir : x;
  int t = threadIdx.x;
  int cg = t & 127, rg = t >> 7;
  int r0 = rblk * 8 + rg * 4;
  const float4* sp = (const float4*)(src + (size_t)r0 * C_) + cg * 2;
  __bf16* dp = dst + (size_t)half * ((size_t)B_ * N_ * C_) + (size_t)r0 * C_ + cg * 8;
  float s[8] = {};
  #pragma unroll
  for (int rr = 0; rr < 4; ++rr) {
    float4 a = sp[0], b4 = sp[1];
    bf16x8 o;
    o[0] = (__bf16)a.x; o[1] = (__bf16)a.y; o[2] = (__bf16)a.z; o[3] = (__bf16)a.w;
    o[4] = (__bf16)b4.x; o[5] = (__bf16)b4.y; o[6] = (__bf16)b4.z; o[7] = (__bf16)b4.w;
    *(bf16x8*)dp = o;
    s[0] += a.x; s[1] += a.y; s[2] += a.z; s[3] += a.w;
    s[4] += b4.x; s[5] += b4.y; s[6] += b4.z; s[7] += b4.w;
    sp += C_ / 4; dp += C_;
  }
  if (half == 0) {
    if (rg == 1) {
      #pragma unroll
      for (int j = 0; j < 8; ++j) red[cg][j] = s[j];
    }
    __syncthreads();
    if (rg == 0) {
      float4 lo, hi;
      lo.x = s[0] + red[cg][0]; lo.y = s[1] + red[cg][1];
      lo.z = s[2] + red[cg][2]; lo.w = s[3] + red[cg][3];
      hi.x = s[4] + red[cg][4]; hi.y = s[5] + red[cg][5];
      hi.z = s[6] + red[cg][6]; hi.w = s[7] + red[cg][7];
      float* pr = pmean + (size_t)rblk * C_ + cg * 8;
      *(float4*)pr = lo;
      *(float4*)(pr + 4) = hi;
    }
  }
}

// ---------------- 2. mean stage 2 (no atomics, no memset; 2 threads/col) ----------
// grid (8 cs, 4 b), block 256: col = cs*128+(t&127), row-half = t>>7 (128 rows each)
__global__ __launch_bounds__(256) void mean2_kernel(const float* __restrict__ pmean,
                                                    float* __restrict__ gx) {
  __shared__ float red[128];
  int cs = blockIdx.x, b = blockIdx.y;
  int t = threadIdx.x;
  int c = cs * 128 + (t & 127), rh = t >> 7;
  const float* p = pmean + ((size_t)b * 256 + rh * 128) * C_ + c;
  float s = 0.f;
  #pragma unroll 8
  for (int j = 0; j < 128; ++j) s += p[(size_t)j * C_];
  if (rh == 1) red[t & 127] = s;
  __syncthreads();
  if (rh == 0) gx[b * C_ + c] = (s + red[t & 127]) * (1.0f / N_);
}

// ---------------- 3. h = relu(gx @ gw1^T + gb1) ----------------
__global__ __launch_bounds__(256) void h_kernel(const float* __restrict__ gx,
    const float* __restrict__ gw1, const float* __restrict__ gb1, float* __restrict__ h) {
  __shared__ float sgx[B_][C_];
  int t = threadIdx.x;
  for (int i = t; i < B_ * C_; i += 256) sgx[i >> 10][i & 1023] = gx[i];
  __syncthreads();
  int jl = t >> 4, l16 = t & 15, b = l16 & 3, qt = l16 >> 2;
  int j = blockIdx.x * 16 + jl;
  const float4* row = (const float4*)(gw1 + (size_t)j * C_) + qt * 64;
  const float* gbase = &sgx[b][qt * 256];
  float acc = 0.f;
  #pragma unroll 8
  for (int c4 = 0; c4 < 64; ++c4) {
    float4 w = row[c4];
    acc += w.x * gbase[c4*4+0] + w.y * gbase[c4*4+1]
         + w.z * gbase[c4*4+2] + w.w * gbase[c4*4+3];
  }
  acc += __shfl_down(acc, 4, 16);
  acc += __shfl_down(acc, 8, 16);
  if (qt == 0) h[b * H_ + j] = fmaxf(acc + gb1[j], 0.f);
}

// ---------------- 4. gates + Wb build (ONE We pass -> all 4 batches) + bb ------
// grid 1024, block 256: thread owns one oc4; loads 8 expert float4s once,
// emits 4 batch outputs. Fetch = 32 MB (was 128 MB).
__global__ __launch_bounds__(256) void wbgate_kernel(const float* __restrict__ h,
    const float* __restrict__ gw2, const float* __restrict__ gb2,
    const float* __restrict__ be, const float* __restrict__ We,
    __bf16* __restrict__ Wb, float* __restrict__ bbp) {
  __shared__ float slog[B_ * E_];
  __shared__ float sg[B_ * E_];
  int t = threadIdx.x;
  int p = t >> 3, sub = t & 7;
  int pb = p >> 3, pe = p & 7;
  float s = 0.f;
  for (int k = sub; k < H_; k += 8) s += h[pb * H_ + k] * gw2[pe * H_ + k];
  s += __shfl_down(s, 4, 8);
  s += __shfl_down(s, 2, 8);
  s += __shfl_down(s, 1, 8);
  if (sub == 0) slog[p] = s + gb2[pe];
  __syncthreads();
  if (t < B_) {
    float m = -1e30f;
    for (int e = 0; e < E_; ++e) m = fmaxf(m, slog[t * E_ + e]);
    float pr[E_], sum = 0.f;
    for (int e = 0; e < E_; ++e) { pr[e] = __expf(slog[t * E_ + e] - m); sum += pr[e]; }
    float inv = 1.f / sum;
    for (int e = 0; e < E_; ++e) sg[t * E_ + e] = pr[e] * inv;
  }
  __syncthreads();

  int bi = blockIdx.x;
  size_t oc4 = (size_t)bi * 256 + t;           // 0 .. 2^18-1
  const float4* src = (const float4*)We + oc4;
  float4 w[E_];
  #pragma unroll
  for (int e = 0; e < E_; ++e) w[e] = src[(size_t)e * (C_ * C_ / 4)];
  #pragma unroll
  for (int b = 0; b < B_; ++b) {
    float4 acc = make_float4(0.f, 0.f, 0.f, 0.f);
    #pragma unroll
    for (int e = 0; e < E_; ++e) {
      float g = sg[b * E_ + e];
      acc.x += g * w[e].x; acc.y += g * w[e].y;
      acc.z += g * w[e].z; acc.w += g * w[e].w;
    }
    bf16x4 o;
    o[0] = (__bf16)acc.x; o[1] = (__bf16)acc.y;
    o[2] = (__bf16)acc.z; o[3] = (__bf16)acc.w;
    *(bf16x4*)(Wb + ((size_t)b << 20) + oc4 * 4) = o;
  }

  if (bi < 16) {                               // bb = g @ be
    int ii = bi * 256 + t;
    int bb_ = ii >> 10, oo = ii & 1023;
    float sbb = 0.f;
    #pragma unroll
    for (int e = 0; e < E_; ++e) sbb += sg[bb_ * E_ + e] * be[e * C_ + oo];
    bbp[ii] = sbb;
  }
}

// ---------------- 5. batched GEMM: out = Xb @ Wb^T + bb  (R4/R8-proven) --------
// 256x256 tile, BK=64, 8 waves (2Mx4N). Stages u0,u1 in P0 and u2,u3 in P1;
// ds_reads pipelined one phase ahead; 3 barriers/tile; counted vmcnt only.
#define NT 16   // K / 64

__global__ __launch_bounds__(512, 2) void moe_gemm(const __bf16* __restrict__ Xb,
    const __bf16* __restrict__ Wb, const float* __restrict__ bb, float* __restrict__ out) {
  __shared__ __attribute__((aligned(128))) char smem[2][65536];

  const int t = threadIdx.x;
  const int wid = t >> 6, lane = t & 63;
  const int wm = wid >> 2, wn = wid & 3;

  // XCD swizzle: one z-slice per XCD
  int f = blockIdx.x;
  int swz = (f & 7) * 32 + (f >> 3);
  int xb_ = swz & 3, yb_ = (swz >> 2) & 7, z = swz >> 5;
  int b = z & 3;
  const size_t mat = (size_t)N_ * C_;
  const __bf16* A  = Xb + (size_t)z * mat;
  const __bf16* Bm = Wb + (size_t)b * C_ * C_;
  float* O = out + (size_t)z * mat;
  const int row0 = yb_ * 256, col0 = xb_ * 256;

  const int lrow8 = lane >> 3;
  const int kblk  = ((lane & 7) ^ lrow8) << 3;

  const int lr = lane & 15;
  const int swzk0 = (((lane >> 4) + 0) ^ (lane & 7)) << 4;
  const int swzk1 = (((lane >> 4) + 4) ^ (lane & 7)) << 4;

  auto stage = [&](int sid, int k0, char* buf) {
    #pragma unroll
    for (int j = 0; j < 2; ++j) {
      int u = wid * 2 + j;
      int rl0 = u * 8;
      if (sid == 0 || sid == 3) {           // A
        int hh = (sid == 3) ? 1 : 0;
        int row_u = rl0 + (rl0 & 64) + hh * 64;
        const __bf16* src = A + (size_t)(row0 + row_u + lrow8) * C_ + k0 + kblk;
        gload16(src, buf + row_u * 128);
      } else {                              // B
        int hh = (sid == 2) ? 1 : 0;
        int col_u = (rl0 & 31) + (rl0 >> 5) * 64 + hh * 32;
        const __bf16* src = Bm + (size_t)(col0 + col_u + lrow8) * C_ + k0 + kblk;
        gload16(src, buf + 32768 + col_u * 128);
      }
    }
  };

  f32x4 acc[8][4] = {};
  bf16x8 av[2][4][2];     // [pipeline buf][mq][ks]
  bf16x8 bv[2][2][2];     // [Bq][nq][ks]

  #define RD_A(buf_, Aq_, mq_) { \
    int rby = (wm * 128 + (Aq_) * 64 + (mq_) * 16 + lr) * 128; \
    av[buf_][mq_][0] = *(const bf16x8*)(rbA + rby + swzk0); \
    av[buf_][mq_][1] = *(const bf16x8*)(rbA + rby + swzk1); }
  #define RD_B(Bq_, nq_) { \
    int cby = (wn * 64 + (Bq_) * 32 + (nq_) * 16 + lr) * 128; \
    bv[Bq_][nq_][0] = *(const bf16x8*)(rbB + cby + swzk0); \
    bv[Bq_][nq_][1] = *(const bf16x8*)(rbB + cby + swzk1); }
  #define MFMA1(ab_, mq_, Bq_, nq_) { \
    acc[(ab_)*4+(mq_)][(Bq_)*2+(nq_)] = __builtin_amdgcn_mfma_f32_16x16x32_bf16( \
        av[ab_][mq_][0], bv[Bq_][nq_][0], acc[(ab_)*4+(mq_)][(Bq_)*2+(nq_)], 0, 0, 0); \
    acc[(ab_)*4+(mq_)][(Bq_)*2+(nq_)] = __builtin_amdgcn_mfma_f32_16x16x32_bf16( \
        av[ab_][mq_][1], bv[Bq_][nq_][1], acc[(ab_)*4+(mq_)][(Bq_)*2+(nq_)], 0, 0, 0); }

  #pragma unroll
  for (int sid = 0; sid < 4; ++sid) stage(sid, 0, smem[0]);
  asm volatile("s_waitcnt vmcnt(2)" ::: "memory");
  __builtin_amdgcn_s_barrier();
  CFENCE();

  for (int kt = 0; kt < NT; ++kt) {
    const char* rbA = smem[kt & 1];
    const char* rbB = rbA + 32768;
    char* wbuf = smem[(kt + 1) & 1];
    const bool more = (kt + 1 < NT);
    const int knext = (kt + 1) * 64;

    // ---- P0: stage u0,u1 | read A0,B0 | MFMA A0xB0 (+lookahead read B1) ----
    if (more) { stage(0, knext, wbuf); stage(1, knext, wbuf); }
    RD_A(0, 0, 0) RD_B(0, 0) RD_A(0, 0, 1) RD_B(0, 1) RD_A(0, 0, 2) RD_A(0, 0, 3)
    __builtin_amdgcn_s_setprio(1);
    MFMA1(0, 0, 0, 0) MFMA1(0, 0, 0, 1)
    RD_B(1, 0) RD_B(1, 1)                          // lookahead for P1
    MFMA1(0, 1, 0, 0) MFMA1(0, 1, 0, 1)
    MFMA1(0, 2, 0, 0) MFMA1(0, 2, 0, 1)
    MFMA1(0, 3, 0, 0) MFMA1(0, 3, 0, 1)
    __builtin_amdgcn_s_setprio(0);
    if (more) asm volatile("s_waitcnt vmcnt(4)" ::: "memory");   // u3(cur) done
    else      asm volatile("s_waitcnt vmcnt(0)" ::: "memory");
    __builtin_amdgcn_s_barrier();
    CFENCE();

    // ---- P1: stage u2,u3 | MFMA A0xB1 (+lookahead read A1) ----
    if (more) { stage(2, knext, wbuf); stage(3, knext, wbuf); }
    __builtin_amdgcn_s_setprio(1);
    MFMA1(0, 0, 1, 0) MFMA1(0, 0, 1, 1)
    RD_A(1, 1, 0) RD_A(1, 1, 1)                    // lookahead for P23
    MFMA1(0, 1, 1, 0) MFMA1(0, 1, 1, 1)
    RD_A(1, 1, 2) RD_A(1, 1, 3)
    MFMA1(0, 2, 1, 0) MFMA1(0, 2, 1, 1)
    MFMA1(0, 3, 1, 0) MFMA1(0, 3, 1, 1)
    __builtin_amdgcn_s_setprio(0);
    __builtin_amdgcn_s_barrier();
    CFENCE();

    // ---- P23: MFMA A1xB0, A1xB1 ----
    __builtin_amdgcn_s_setprio(1);
    MFMA1(1, 0, 0, 0) MFMA1(1, 0, 0, 1) MFMA1(1, 1, 0, 0) MFMA1(1, 1, 0, 1)
    MFMA1(1, 2, 0, 0) MFMA1(1, 2, 0, 1) MFMA1(1, 3, 0, 0) MFMA1(1, 3, 0, 1)
    MFMA1(1, 0, 1, 0) MFMA1(1, 0, 1, 1) MFMA1(1, 1, 1, 0) MFMA1(1, 1, 1, 1)
    MFMA1(1, 2, 1, 0) MFMA1(1, 2, 1, 1) MFMA1(1, 3, 1, 0) MFMA1(1, 3, 1, 1)
    __builtin_amdgcn_s_setprio(0);
    if (more) asm volatile("s_waitcnt vmcnt(2)" ::: "memory");   // u0,u1,u2(next) done
    __builtin_amdgcn_s_barrier();
    CFENCE();
  }

  // ---- coalesced epilogue via per-wave LDS transpose (16 x 68 f32) ----
  float* eb = (float*)(smem[0]) + wid * (16 * 68);
  const int er = lane >> 4;
  const f32x4 bias4 = *(const f32x4*)(bb + b * C_ + col0 + wn * 64 + lr * 4);

  #pragma unroll
  for (int m = 0; m < 8; ++m) {
    #pragma unroll
    for (int n = 0; n < 4; ++n) {
      f32x4 v = acc[m][n];
      #pragma unroll
      for (int r = 0; r < 4; ++r)
        eb[(er * 4 + r) * 68 + n * 16 + lr] = v[r];
    }
    asm volatile("s_waitcnt lgkmcnt(0)" ::: "memory");
    __builtin_amdgcn_sched_barrier(0);
    #pragma unroll
    for (int j = 0; j < 4; ++j) {
      int row = j * 4 + er;
      f32x4 v = *(const f32x4*)(eb + row * 68 + lr * 4);
      v[0] += bias4[0]; v[1] += bias4[1]; v[2] += bias4[2]; v[3] += bias4[3];
      int grow = row0 + wm * 128 + m * 16 + row;
      int gcol = col0 + wn * 64 + lr * 4;
      *(f32x4*)(O + (size_t)grow * C_ + gcol) = v;
    }
    asm volatile("s_waitcnt lgkmcnt(0)" ::: "memory");
  }
}

// ---------------- launcher ----------------
extern "C" void kernel_launch(void* const* d_in, const int* in_sizes, int n_in,
                              void* d_out, int out_size, void* d_ws, size_t ws_size,
                              hipStream_t stream) {
  const float* x    = (const float*)d_in[0];
  const float* x_ir = (const float*)d_in[1];
  const float* We   = (const float*)d_in[2];
  const float* be   = (const float*)d_in[3];
  const float* gw1  = (const float*)d_in[4];
  const float* gb1  = (const float*)d_in[5];
  const float* gw2  = (const float*)d_in[6];
  const float* gb2  = (const float*)d_in[7];
  float* out = (float*)d_out;

  char* ws = (char*)d_ws;
  __bf16* Wb    = (__bf16*)(ws + WB_OFF);
  float*  pmean = (float*)(ws + PM_OFF);   // overlaps Wb (ordered: mean2 < wbgate)
  __bf16* Xb    = (__bf16*)(ws + XB_OFF);
  float*  gx    = (float*)(ws + GX_OFF);
  float*  bbp   = (float*)(ws + BB_OFF);
  float*  h     = (float*)(ws + H_OFF);

  castmean_kernel<<<2048, 256, 0, stream>>>(x, x_ir, Xb, pmean);
  mean2_kernel<<<dim3(8, 4), 256, 0, stream>>>(pmean, gx);
  h_kernel<<<32, 256, 0, stream>>>(gx, gw1, gb1, h);
  wbgate_kernel<<<1024, 256, 0, stream>>>(h, gw2, gb2, be, We, Wb, bbp);

  moe_gemm<<<256, 512, 0, stream>>>(Xb, Wb, bbp, out);
}